// Round 4
// baseline (742.474 us; speedup 1.0000x reference)
//
#include <hip/hip_runtime.h>
#include <stdint.h>

// ---- problem constants ----
#define BB   8
#define LL   8192
#define HH   8
#define DH   64
#define DIMM 512
#define KS_  13
// dilation = 2, ns = 6
// ALL inputs and the output are float32 (per the reference). Q/K/V
// intermediates are bf16 in workspace (MFMA needs bf16; no fp32 MFMA).

typedef unsigned short ushort_t;
typedef __attribute__((ext_vector_type(8))) short bf16x8;   // 8 x bf16 (4 VGPRs)
typedef __attribute__((ext_vector_type(4))) float f32x4;

__device__ __forceinline__ float bf2f(unsigned short h) {
    return __uint_as_float(((unsigned)h) << 16);
}
__device__ __forceinline__ unsigned short f2bf(float f) {
    unsigned u = __float_as_uint(f);
    u += 0x7fffu + ((u >> 16) & 1u);       // round-to-nearest-even
    return (unsigned short)(u >> 16);
}
__device__ __forceinline__ void unpack8(uint4 u, float* f) {
    f[0] = __uint_as_float(u.x << 16); f[1] = __uint_as_float(u.x & 0xffff0000u);
    f[2] = __uint_as_float(u.y << 16); f[3] = __uint_as_float(u.y & 0xffff0000u);
    f[4] = __uint_as_float(u.z << 16); f[5] = __uint_as_float(u.z & 0xffff0000u);
    f[6] = __uint_as_float(u.w << 16); f[7] = __uint_as_float(u.w & 0xffff0000u);
}
__device__ __forceinline__ uint4 pack8(const float4 a, const float4 b) {
    uint4 u;
    u.x = (unsigned)f2bf(a.x) | ((unsigned)f2bf(a.y) << 16);
    u.y = (unsigned)f2bf(a.z) | ((unsigned)f2bf(a.w) << 16);
    u.z = (unsigned)f2bf(b.x) | ((unsigned)f2bf(b.y) << 16);
    u.w = (unsigned)f2bf(b.z) | ((unsigned)f2bf(b.w) << 16);
    return u;
}

// ---------------------------------------------------------------------------
// Kernel 0: convert+transpose the three f32 512x512 weights into bf16
// Wt [1536][512] (n-major: Wt[n][k] = W[k][n])
// ---------------------------------------------------------------------------
__global__ void transpose512(const float* __restrict__ Wq,
                             const float* __restrict__ Wk,
                             const float* __restrict__ Wv,
                             ushort_t* __restrict__ Wt) {
    __shared__ float tile[32][33];
    int mtx = blockIdx.z;
    const float* src = (mtx == 0) ? Wq : ((mtx == 1) ? Wk : Wv);
    ushort_t* dst = Wt + (size_t)mtx * 512 * 512;
    int bx = blockIdx.x * 32, by = blockIdx.y * 32;
    int tx = threadIdx.x, ty = threadIdx.y;
    #pragma unroll
    for (int i = 0; i < 32; i += 8)
        tile[ty + i][tx] = src[(size_t)(by + ty + i) * 512 + bx + tx];
    __syncthreads();
    #pragma unroll
    for (int i = 0; i < 32; i += 8)
        dst[(size_t)(bx + ty + i) * 512 + by + tx] = f2bf(tile[tx][ty + i]);
}

// ---------------------------------------------------------------------------
// Kernel 1: per-batch QKV GEMM.  C[8192,512] = A[8192,512] @ W  (3 weights)
// A is f32 (converted to bf16 during staging); Wt is bf16 (pre-converted).
// 128x128 tile, 4 waves, 4x4 mfma_16x16x32_bf16, BK=32, 2-barrier staging.
// ---------------------------------------------------------------------------
__global__ __launch_bounds__(256) void qkv_gemm(
    const float* __restrict__ A,       // [8192, 512] f32 (one batch of hidden)
    const ushort_t* __restrict__ Wt,   // [1536, 512] bf16 (W^T, q|k|v)
    const float* __restrict__ bq,
    const float* __restrict__ bk,
    const float* __restrict__ bv,
    ushort_t* __restrict__ Qo,         // [8192, 512] bf16 each
    ushort_t* __restrict__ Ko,
    ushort_t* __restrict__ Vo) {
    __shared__ ushort_t sA[128 * 32];
    __shared__ ushort_t sB[128 * 32];

    const int t  = threadIdx.x;
    const int m0 = blockIdx.y * 128;          // 0..8063
    const int ng = blockIdx.x * 128;          // 0..1408
    const int mtx = ng >> 9;
    const float* bias = (mtx == 0) ? bq : ((mtx == 1) ? bk : bv);
    ushort_t* Co = (mtx == 0) ? Qo : ((mtx == 1) ? Ko : Vo);
    const float scale = (mtx == 0) ? 0.125f : 1.0f;   // 1/sqrt(DH) on q
    const int n0 = ng & 511;

    const int lane = t & 63;
    const int w    = t >> 6;
    const int wm   = w >> 1, wn = w & 1;
    const int md   = lane & 15, qd = lane >> 4;

    f32x4 acc[4][4];
    const f32x4 zero = {0.f, 0.f, 0.f, 0.f};
    #pragma unroll
    for (int i = 0; i < 4; ++i)
        #pragma unroll
        for (int j = 0; j < 4; ++j) acc[i][j] = zero;

    // staging: each thread covers 8 consecutive K-elements of one row
    const int ar = t >> 2;                 // 0..63
    const int ac = (t & 3) * 8;            // element offset within the 32-wide K tile... cols 0..31
    const float*    gA0 = A  + (size_t)(m0 + ar) * 512 + ac;   // f32
    const float*    gA1 = gA0 + (size_t)64 * 512;
    const ushort_t* gB0 = Wt + (size_t)(ng + ar) * 512 + ac;   // bf16
    const ushort_t* gB1 = gB0 + (size_t)64 * 512;
    ushort_t* lA0 = sA + t * 8;            // lane-linear, row-major [128][32]
    ushort_t* lA1 = sA + 2048 + t * 8;
    ushort_t* lB0 = sB + t * 8;
    ushort_t* lB1 = sB + 2048 + t * 8;

    const int aoff[4] = { (wm * 64 +  0 + md) * 32 + qd * 8,
                          (wm * 64 + 16 + md) * 32 + qd * 8,
                          (wm * 64 + 32 + md) * 32 + qd * 8,
                          (wm * 64 + 48 + md) * 32 + qd * 8 };
    const int boff[4] = { (wn * 64 +  0 + md) * 32 + qd * 8,
                          (wn * 64 + 16 + md) * 32 + qd * 8,
                          (wn * 64 + 32 + md) * 32 + qd * 8,
                          (wn * 64 + 48 + md) * 32 + qd * 8 };

    for (int kk = 0; kk < 16; ++kk) {
        // global -> VGPR; A converts f32 -> bf16 in registers
        float4 a0lo = *(const float4*)(gA0 + kk * 32);
        float4 a0hi = *(const float4*)(gA0 + kk * 32 + 4);
        float4 a1lo = *(const float4*)(gA1 + kk * 32);
        float4 a1hi = *(const float4*)(gA1 + kk * 32 + 4);
        uint4 b0 = *(const uint4*)(gB0 + kk * 32);
        uint4 b1 = *(const uint4*)(gB1 + kk * 32);
        uint4 a0 = pack8(a0lo, a0hi);
        uint4 a1 = pack8(a1lo, a1hi);
        __syncthreads();                    // previous iteration's LDS readers done
        *(uint4*)lA0 = a0;
        *(uint4*)lA1 = a1;
        *(uint4*)lB0 = b0;
        *(uint4*)lB1 = b1;
        __syncthreads();

        bf16x8 af[4], bfv[4];
        #pragma unroll
        for (int mi = 0; mi < 4; ++mi) af[mi]  = *(const bf16x8*)&sA[aoff[mi]];
        #pragma unroll
        for (int ni = 0; ni < 4; ++ni) bfv[ni] = *(const bf16x8*)&sB[boff[ni]];

        #pragma unroll
        for (int mi = 0; mi < 4; ++mi)
            #pragma unroll
            for (int ni = 0; ni < 4; ++ni)
                acc[mi][ni] = __builtin_amdgcn_mfma_f32_16x16x32_bf16(
                    af[mi], bfv[ni], acc[mi][ni], 0, 0, 0);
    }

    // epilogue: D[row][col], row = qd*4 + r, col = md (verified m89/m91 layout)
    #pragma unroll
    for (int ni = 0; ni < 4; ++ni) {
        const int col = n0 + wn * 64 + ni * 16 + md;
        const float bv_ = bias[col];
        #pragma unroll
        for (int mi = 0; mi < 4; ++mi) {
            const int rbase = m0 + wm * 64 + mi * 16 + qd * 4;
            #pragma unroll
            for (int r = 0; r < 4; ++r) {
                float v = (acc[mi][ni][r] + bv_) * scale;
                Co[(size_t)(rbase + r) * 512 + col] = f2bf(v);
            }
        }
    }
}

// ---------------------------------------------------------------------------
// Kernel 2: per-batch NA1D attention (KS=13, dilation=2), one thread per (l,h).
// Q/K/V bf16; rpb f32; output O f32.
// ---------------------------------------------------------------------------
__global__ __launch_bounds__(128) void na1d_attn(
    const ushort_t* __restrict__ Q,     // [8192, 512] bf16
    const ushort_t* __restrict__ K,
    const ushort_t* __restrict__ V,
    const float* __restrict__ rpb,      // [8][25] f32
    float* __restrict__ O) {            // [8192, 512] f32 (one batch of out)
    __shared__ ushort_t sKV[152 * 72];  // rows padded 64 -> 72 el

    const int t  = threadIdx.x;
    const int l0 = blockIdx.x * 128;
    const int h  = blockIdx.y;

    int p_lo = l0 - 12; if (p_lo < 0) p_lo = 0;
    int p_hi = l0 + 127 + 12; if (p_hi > LL - 1) p_hi = LL - 1;
    const int rows = p_hi - p_lo + 1;   // <= 152

    const size_t kvbase = (size_t)p_lo * DIMM + h * DH;
    const int sc_ = (t & 7) * 8;

    // ---- stage K window ----
    for (int r = t >> 3; r < rows; r += 16)
        *(uint4*)&sKV[r * 72 + sc_] = *(const uint4*)(K + kvbase + (size_t)r * DIMM + sc_);
    __syncthreads();

    const int l   = l0 + t;
    const int par = l & 1;
    const bool lo_e = (l < 12);
    const bool hi_e = (l + 12) >= LL;
    const int ws = lo_e ? par : (hi_e ? (LL - 26 + par) : (l - 12));
    const int ps = lo_e ? (12 - (l >> 1)) : (hi_e ? ((LL - 1 - l) >> 1) : 6);
    const int r0 = ws - p_lo;

    // ---- q into registers ----
    float qf[64];
    const uint4* qg = (const uint4*)(Q + (size_t)l * DIMM + h * DH);
    #pragma unroll
    for (int c = 0; c < 8; ++c) {
        uint4 u = qg[c];
        unpack8(u, &qf[c * 8]);
    }

    // ---- scores ----
    float sc[13];
    #pragma unroll
    for (int j = 0; j < 13; ++j) {
        const uint4* kp = (const uint4*)&sKV[(unsigned)(r0 + 2 * j) * 72];
        float a0 = 0.f, a1 = 0.f;
        #pragma unroll
        for (int c = 0; c < 8; ++c) {
            uint4 u = kp[c];
            float f[8]; unpack8(u, f);
            a0 += qf[c * 8 + 0] * f[0]; a1 += qf[c * 8 + 1] * f[1];
            a0 += qf[c * 8 + 2] * f[2]; a1 += qf[c * 8 + 3] * f[3];
            a0 += qf[c * 8 + 4] * f[4]; a1 += qf[c * 8 + 5] * f[5];
            a0 += qf[c * 8 + 6] * f[6]; a1 += qf[c * 8 + 7] * f[7];
        }
        sc[j] = a0 + a1 + rpb[h * 25 + ps + j];
    }

    // ---- softmax (per-thread, no cross-lane) ----
    float mx = sc[0];
    #pragma unroll
    for (int j = 1; j < 13; ++j) mx = fmaxf(mx, sc[j]);
    float sum = 0.f;
    #pragma unroll
    for (int j = 0; j < 13; ++j) { sc[j] = __expf(sc[j] - mx); sum += sc[j]; }
    const float inv = 1.0f / sum;
    #pragma unroll
    for (int j = 0; j < 13; ++j) sc[j] *= inv;

    // ---- stage V window into the same LDS ----
    __syncthreads();
    for (int r = t >> 3; r < rows; r += 16)
        *(uint4*)&sKV[r * 72 + sc_] = *(const uint4*)(V + kvbase + (size_t)r * DIMM + sc_);
    __syncthreads();

    // ---- weighted sum ----
    float of[64];
    #pragma unroll
    for (int d = 0; d < 64; ++d) of[d] = 0.f;
    #pragma unroll
    for (int j = 0; j < 13; ++j) {
        const uint4* vp = (const uint4*)&sKV[(unsigned)(r0 + 2 * j) * 72];
        const float wj = sc[j];
        #pragma unroll
        for (int c = 0; c < 8; ++c) {
            uint4 u = vp[c];
            float f[8]; unpack8(u, f);
            #pragma unroll
            for (int e = 0; e < 8; ++e) of[c * 8 + e] += wj * f[e];
        }
    }

    // ---- store f32 ----
    float4* og = (float4*)(O + (size_t)l * DIMM + h * DH);
    #pragma unroll
    for (int c = 0; c < 16; ++c) {
        float4 u;
        u.x = of[c * 4 + 0]; u.y = of[c * 4 + 1];
        u.z = of[c * 4 + 2]; u.w = of[c * 4 + 3];
        og[c] = u;
    }
}

// ---------------------------------------------------------------------------
extern "C" void kernel_launch(void* const* d_in, const int* in_sizes, int n_in,
                              void* d_out, int out_size, void* d_ws, size_t ws_size,
                              hipStream_t stream) {
    const float* hid = (const float*)d_in[0];
    const float* Wq  = (const float*)d_in[1];
    const float* bq  = (const float*)d_in[2];
    const float* Wk  = (const float*)d_in[3];
    const float* bk  = (const float*)d_in[4];
    const float* Wv  = (const float*)d_in[5];
    const float* bv  = (const float*)d_in[6];
    const float* rpb = (const float*)d_in[7];
    float* out = (float*)d_out;

    // workspace (bf16): Wt (1536*512) + per-batch Q/K/V (8192*512 each) = 26.7 MB
    ushort_t* ws = (ushort_t*)d_ws;
    ushort_t* Wt = ws;
    ushort_t* Qb = Wt + (size_t)1536 * 512;
    ushort_t* Kb = Qb + (size_t)LL * DIMM;
    ushort_t* Vb = Kb + (size_t)LL * DIMM;

    transpose512<<<dim3(16, 16, 3), dim3(32, 8), 0, stream>>>(Wq, Wk, Wv, Wt);
    for (int b = 0; b < BB; ++b) {
        const float* hb = hid + (size_t)b * LL * DIMM;
        float*       ob = out + (size_t)b * LL * DIMM;
        qkv_gemm<<<dim3(12, 64), 256, 0, stream>>>(hb, Wt, bq, bk, bv, Qb, Kb, Vb);
        na1d_attn<<<dim3(LL / 128, HH), 128, 0, stream>>>(Qb, Kb, Vb, rpb, ob);
    }
}